// Round 4
// baseline (57820.764 us; speedup 1.0000x reference)
//
#include <hip/hip_runtime.h>
#include <cstdint>

// ---------------------------------------------------------------------------
// conv1_k: 1 pixel/thread, 16x16 tile, CIS input channels staged per barrier,
// COB output channels per block. Used for Cin=3 (L0) and H=16 (L10).
// ---------------------------------------------------------------------------
template <int CIS, int COB>
__global__ __launch_bounds__(256, 4) void conv1_k(
    const float* __restrict__ in, const float* __restrict__ wgt,
    const float* __restrict__ bias, float* __restrict__ out,
    int Cin, int Cout, int H, int W)
{
    const int tilesX = W >> 4;
    const int tx = blockIdx.x % tilesX;
    const int ty = blockIdx.x / tilesX;
    const int x0 = tx << 4, y0 = ty << 4;
    const int co0 = blockIdx.y * COB;
    const int n = blockIdx.z;
    in  += (size_t)n * Cin * H * W;
    out += (size_t)n * Cout * H * W;

    __shared__ float tile[CIS][18][20];

    const int tid = threadIdx.x;
    const int lx = tid & 15, ly = tid >> 4;
    const int ox = x0 + lx, oy = y0 + ly;

    float acc[COB];
#pragma unroll
    for (int i = 0; i < COB; ++i) acc[i] = 0.f;

    for (int ci0 = 0; ci0 < Cin; ci0 += CIS) {
        for (int t = tid; t < CIS * 324; t += 256) {
            int s = t / 324;
            int rem = t - s * 324;
            int r = rem / 18, c = rem - r * 18;
            int gy = y0 - 1 + r, gx = x0 - 1 + c;
            const float* ip = in + (size_t)(ci0 + s) * H * W;
            float v = 0.f;
            if (gy >= 0 && gy < H && gx >= 0 && gx < W) v = ip[(size_t)gy * W + gx];
            tile[s][r][c] = v;
        }
        __syncthreads();
#pragma unroll
        for (int s = 0; s < CIS; ++s) {
            float p[3][3];
#pragma unroll
            for (int r = 0; r < 3; ++r)
#pragma unroll
                for (int c = 0; c < 3; ++c)
                    p[r][c] = tile[s][ly + r][lx + c];
            const float* wp = wgt + ((size_t)co0 * Cin + (ci0 + s)) * 9;
#pragma unroll
            for (int co = 0; co < COB; ++co) {
                const float* wc = wp + (size_t)co * Cin * 9;
#pragma unroll
                for (int k = 0; k < 9; ++k)
                    acc[co] = fmaf(p[k / 3][k % 3], wc[k], acc[co]);
            }
        }
        __syncthreads();
    }
#pragma unroll
    for (int co = 0; co < COB; ++co) {
        float v = acc[co] + bias[co0 + co];
        v = v > 0.f ? v : 0.f;
        out[(size_t)(co0 + co) * H * W + (size_t)oy * W + ox] = v;
    }
}

// ---------------------------------------------------------------------------
// conv2x2_k: 2x2 pixels/thread, 32x32 tile, 4 input channels staged per
// barrier, COB output channels per block. Used for H>=32 layers (Cin%4==0).
// COB=8 targets 4 blocks/CU (VGPR<=128); COB=16 runs 2 blocks/CU.
// ---------------------------------------------------------------------------
template <int COB>
__global__ __launch_bounds__(256, (COB == 16 ? 2 : 4)) void conv2x2_k(
    const float* __restrict__ in, const float* __restrict__ wgt,
    const float* __restrict__ bias, float* __restrict__ out,
    int Cin, int Cout, int H, int W)
{
    const int tilesX = W >> 5;
    const int tx = blockIdx.x % tilesX;
    const int ty = blockIdx.x / tilesX;
    const int x0 = tx << 5, y0 = ty << 5;
    const int co0 = blockIdx.y * COB;
    const int n = blockIdx.z;
    in  += (size_t)n * Cin * H * W;
    out += (size_t)n * Cout * H * W;

    __shared__ float tile[4][34][36];

    const int tid = threadIdx.x;
    const int lx = tid & 15, ly = tid >> 4;  // thread owns 2x2 at (y0+2ly, x0+2lx)
    const int oy = y0 + 2 * ly, ox = x0 + 2 * lx;

    float acc[COB][2][2];
#pragma unroll
    for (int co = 0; co < COB; ++co)
#pragma unroll
        for (int dy = 0; dy < 2; ++dy)
#pragma unroll
            for (int dx = 0; dx < 2; ++dx) acc[co][dy][dx] = 0.f;

    for (int ci0 = 0; ci0 < Cin; ci0 += 4) {
        for (int t = tid; t < 4 * 1156; t += 256) {
            int s = t / 1156;
            int rem = t - s * 1156;
            int r = rem / 34, c = rem - r * 34;
            int gy = y0 - 1 + r, gx = x0 - 1 + c;
            const float* ip = in + (size_t)(ci0 + s) * H * W;
            float v = 0.f;
            if (gy >= 0 && gy < H && gx >= 0 && gx < W) v = ip[(size_t)gy * W + gx];
            tile[s][r][c] = v;
        }
        __syncthreads();
#pragma unroll
        for (int s = 0; s < 4; ++s) {
            float patch[4][4];
#pragma unroll
            for (int r = 0; r < 4; ++r) {
                const float* row = &tile[s][2 * ly + r][2 * lx];
#pragma unroll
                for (int c = 0; c < 4; ++c) patch[r][c] = row[c];
            }
            const float* wp = wgt + ((size_t)co0 * Cin + (ci0 + s)) * 9;
#pragma unroll
            for (int co = 0; co < COB; ++co) {
                const float* wc = wp + (size_t)co * Cin * 9;
#pragma unroll
                for (int kr = 0; kr < 3; ++kr)
#pragma unroll
                    for (int kc = 0; kc < 3; ++kc) {
                        float wv = wc[kr * 3 + kc];
                        acc[co][0][0] = fmaf(patch[kr][kc],         wv, acc[co][0][0]);
                        acc[co][0][1] = fmaf(patch[kr][kc + 1],     wv, acc[co][0][1]);
                        acc[co][1][0] = fmaf(patch[kr + 1][kc],     wv, acc[co][1][0]);
                        acc[co][1][1] = fmaf(patch[kr + 1][kc + 1], wv, acc[co][1][1]);
                    }
            }
        }
        __syncthreads();
    }
#pragma unroll
    for (int co = 0; co < COB; ++co) {
        float bv = bias[co0 + co];
        float* op = out + (size_t)(co0 + co) * H * W + (size_t)oy * W + ox;
#pragma unroll
        for (int dy = 0; dy < 2; ++dy) {
            float v0 = acc[co][dy][0] + bv; v0 = v0 > 0.f ? v0 : 0.f;
            float v1 = acc[co][dy][1] + bv; v1 = v1 > 0.f ? v1 : 0.f;
            *reinterpret_cast<float2*>(op + (size_t)dy * W) = make_float2(v0, v1);
        }
    }
}

// 2x2 maxpool. W is a power of two; wshift = log2(W). grid: (pixels/256, Ct).
__global__ __launch_bounds__(256) void maxpool2x2_k(
    const float* __restrict__ in, float* __restrict__ out,
    int wshift)
{
    const int W = 1 << wshift, Wo = W >> 1;
    const int c = blockIdx.y;
    const int p = blockIdx.x * 256 + threadIdx.x;  // pixel in output plane
    const int yo = p >> (wshift - 1);
    const int xo = p & (Wo - 1);
    const float* ip = in + ((size_t)c << (2 * wshift)) + (size_t)(2 * yo) * W + 2 * xo;
    float v0 = fmaxf(ip[0], ip[1]);
    float v1 = fmaxf(ip[W], ip[W + 1]);
    out[((size_t)c << (2 * wshift - 2)) + p] = fmaxf(v0, v1);
}

// Bilinear feature align replicating the reference's edge-weight quirks.
__global__ __launch_bounds__(256) void align_k(
    const float* __restrict__ feat, const float* __restrict__ pts,
    const int* __restrict__ mask, float* __restrict__ out,
    int B, int C, int H, int P)
{
    const int p = blockIdx.x, b = blockIdx.y;
    const int W = H;
    int ns = 0;
    for (int i = 0; i < P; ++i) ns += mask[b * P + i];
    const float valid = (p < ns) ? 1.f : 0.f;
    const float px = pts[((size_t)b * P + p) * 2 + 0];
    const float py = pts[((size_t)b * P + p) * 2 + 1];
    const float step = 256.0f / (float)H;
    const float x = (px - step * 0.5f) / 256.0f * (float)H;
    const float y = (py - step * 0.5f) / 256.0f * (float)W;
    const float x0f = floorf(x), y0f = floorf(y);
    const int x0 = min(max((int)x0f, 0), W - 1);
    const int x1 = min(max((int)x0f + 1, 0), W - 1);
    const int y0 = min(max((int)y0f, 0), H - 1);
    const int y1 = min(max((int)y0f + 1, 0), H - 1);
    const bool xe = (x0 == x1), ye = (y0 == y1);
    const float x0w = (xe && x0 == 0) ? -1.f : (float)x0;
    const float x1w = (xe && x0 != 0) ? (float)(x1 + 1) : (float)x1;
    const float y0w = (ye && y0 == 0) ? -1.f : (float)y0;
    const float y1w = (ye && y0 != 0) ? (float)(y1 + 1) : (float)y1;
    const float wa = (x1w - x) * (y1w - y);
    const float wb = (x1w - x) * (y - y0w);
    const float wc = (x - x0w) * (y1w - y);
    const float wd = (x - x0w) * (y - y0w);
    const float* f = feat + (size_t)b * C * H * W;
    for (int c = threadIdx.x; c < C; c += blockDim.x) {
        const float* fc = f + (size_t)c * H * W;
        float Ia = fc[y0 * W + x0];
        float Ib = fc[y1 * W + x0];
        float Ic = fc[y0 * W + x1];
        float Id = fc[y1 * W + x1];
        float v = Ia * wa + Ib * wb + Ic * wc + Id * wd;
        out[((size_t)b * P + p) * C + c] = v * valid;
    }
}

// Layer-shape-aware dispatch.
static inline void conv_auto(const float* in, const float* w, const float* b,
                             float* out, int N, int Cin, int Cout, int H,
                             hipStream_t s)
{
    if (Cin == 3) {                        // L0
        int t = H >> 4;
        conv1_k<3, 8><<<dim3(t * t, Cout / 8, N), 256, 0, s>>>(in, w, b, out, Cin, Cout, H, H);
    } else if (H >= 128) {                 // L1..L3: big grids -> COB=16
        int t = H >> 5;
        conv2x2_k<16><<<dim3(t * t, Cout / 16, N), 256, 0, s>>>(in, w, b, out, Cin, Cout, H, H);
    } else if (H >= 32) {                  // L4..L9: COB=8 (L4-6: 4 blk/CU, L7-9: 2 blk/CU A/B)
        int t = H >> 5;
        conv2x2_k<8><<<dim3(t * t, Cout / 8, N), 256, 0, s>>>(in, w, b, out, Cin, Cout, H, H);
    } else {                               // H=16 (L10)
        int t = H >> 4;
        conv1_k<4, 8><<<dim3(t * t, Cout / 8, N), 256, 0, s>>>(in, w, b, out, Cin, Cout, H, H);
    }
}

static inline void launch_pool(const float* in, float* out, int Ct, int H,
                               hipStream_t s)
{
    int wshift = 31 - __builtin_clz((unsigned)H);
    int pixels = (H >> 1) * (H >> 1);
    dim3 g((pixels + 255) / 256, Ct);
    maxpool2x2_k<<<g, 256, 0, s>>>(in, out, wshift);
}

// Full network given ping-pong buffers sized >= per-call maxima.
// Writes F (512@32^2) slices to Fout and U (512@16^2) slices to Uout.
static void run_net(const float* x, const float* const* w, const float* const* bb,
                    float* p0, float* p1, float* Fout, float* Uout,
                    int N, hipStream_t s)
{
    conv_auto(x,  w[0], bb[0], p0, N, 3, 64, 256, s);
    conv_auto(p0, w[1], bb[1], p1, N, 64, 64, 256, s);
    launch_pool(p1, p0, N * 64, 256, s);                 // 64@128^2
    conv_auto(p0, w[2], bb[2], p1, N, 64, 128, 128, s);
    conv_auto(p1, w[3], bb[3], p0, N, 128, 128, 128, s);
    launch_pool(p0, p1, N * 128, 128, s);                // 128@64^2
    conv_auto(p1, w[4], bb[4], p0, N, 128, 256, 64, s);
    conv_auto(p0, w[5], bb[5], p1, N, 256, 256, 64, s);
    conv_auto(p1, w[6], bb[6], p0, N, 256, 256, 64, s);
    launch_pool(p0, p1, N * 256, 64, s);                 // 256@32^2
    conv_auto(p1, w[7], bb[7], p0, N, 256, 512, 32, s);
    conv_auto(p0, w[8], bb[8], Fout, N, 512, 512, 32, s);   // F
    conv_auto(Fout, w[9], bb[9], p0, N, 512, 512, 32, s);
    launch_pool(p0, p1, N * 512, 32, s);                 // 512@16^2
    conv_auto(p1, w[10], bb[10], Uout, N, 512, 512, 16, s); // U
}

extern "C" void kernel_launch(void* const* d_in, const int* in_sizes, int n_in,
                              void* d_out, int out_size, void* d_ws, size_t ws_size,
                              hipStream_t stream)
{
    const float* x   = (const float*)d_in[0];
    const float* pts = (const float*)d_in[1];
    const int*   msk = (const int*)d_in[2];
    const float* w[11]; const float* bb[11];
    for (int i = 0; i < 11; ++i) {
        w[i]  = (const float*)d_in[3 + 2 * i];
        bb[i] = (const float*)d_in[4 + 2 * i];
    }
    float* out = (float*)d_out;
    float* ws = (float*)d_ws;

    // Batched tier: two 33.55M-float ping-pongs + F(4.19M) + U(1.05M) = 289.4 MB
    const size_t T1_FLOATS = 2ull * 33554432ull + 4194304ull + 1048576ull;

    const float* Fmap; const float* Umap;

    if (ws_size >= T1_FLOATS * 4) {
        float* p0 = ws;
        float* p1 = p0 + 33554432;
        float* F  = p1 + 33554432;
        float* U  = F + 4194304;
        run_net(x, w, bb, p0, p1, F, U, 8, stream);
        Fmap = F; Umap = U;
    } else {
        // fully per-image fallback (needs 54.5 MB)
        float* p0 = ws;
        float* p1 = p0 + 4194304;
        float* F  = p1 + 4194304;
        float* U  = F + 4194304;
        for (int n = 0; n < 8; ++n) {
            run_net(x + (size_t)n * 3 * 65536, w, bb, p0, p1,
                    F + (size_t)n * 512 * 1024, U + (size_t)n * 512 * 256, 1, stream);
        }
        Fmap = F; Umap = U;
    }

    dim3 g(32, 8);
    align_k<<<g, 256, 0, stream>>>(Fmap, pts, msk, out,          8, 512, 32, 32);
    align_k<<<g, 256, 0, stream>>>(Umap, pts, msk, out + 131072, 8, 512, 16, 32);
}

// Round 7
// 9996.118 us; speedup vs baseline: 5.7843x; 5.7843x over previous
//
#include <hip/hip_runtime.h>
#include <cstdint>

// ---------------------------------------------------------------------------
// conv1_k: 1 px/thread, 16x16 tile, CIS input channels per barrier stage,
// COB output channels per block. Weights staged in LDS (broadcast reads).
// Used for Cin=3 (L0) and H<=32 (L7..L10).
// ---------------------------------------------------------------------------
template <int CIS, int COB>
__global__ __launch_bounds__(256, 4) void conv1_k(
    const float* __restrict__ in, const float* __restrict__ wgt,
    const float* __restrict__ bias, float* __restrict__ out,
    int Cin, int Cout, int H, int W)
{
    const int tilesX = W >> 4;
    const int tx = blockIdx.x % tilesX;
    const int ty = blockIdx.x / tilesX;
    const int x0 = tx << 4, y0 = ty << 4;
    const int co0 = blockIdx.y * COB;
    const int n = blockIdx.z;
    in  += (size_t)n * Cin * H * W;
    out += (size_t)n * Cout * H * W;

    __shared__ float tile[CIS][18][20];
    __shared__ float wlds[CIS][COB][12];

    const int tid = threadIdx.x;
    const int lx = tid & 15, ly = tid >> 4;
    const int ox = x0 + lx, oy = y0 + ly;

    float acc[COB];
#pragma unroll
    for (int i = 0; i < COB; ++i) acc[i] = 0.f;

    for (int ci0 = 0; ci0 < Cin; ci0 += CIS) {
        for (int t = tid; t < CIS * 324; t += 256) {
            int s = t / 324;
            int rem = t - s * 324;
            int r = rem / 18, c = rem - r * 18;
            int gy = y0 - 1 + r, gx = x0 - 1 + c;
            const float* ip = in + (size_t)(ci0 + s) * H * W;
            float v = 0.f;
            if (gy >= 0 && gy < H && gx >= 0 && gx < W) v = ip[(size_t)gy * W + gx];
            tile[s][r][c] = v;
        }
        for (int t = tid; t < CIS * COB * 9; t += 256) {
            int co = t / (CIS * 9);
            int r  = t - co * (CIS * 9);
            int s  = r / 9, k = r - s * 9;
            wlds[s][co][k] = wgt[((size_t)(co0 + co) * Cin + (ci0 + s)) * 9 + k];
        }
        __syncthreads();
#pragma unroll
        for (int s = 0; s < CIS; ++s) {
            float p[3][3];
#pragma unroll
            for (int r = 0; r < 3; ++r)
#pragma unroll
                for (int c = 0; c < 3; ++c)
                    p[r][c] = tile[s][ly + r][lx + c];
#pragma unroll
            for (int co = 0; co < COB; ++co) {
                float wr[9];
#pragma unroll
                for (int k = 0; k < 9; ++k) wr[k] = wlds[s][co][k];
#pragma unroll
                for (int k = 0; k < 9; ++k)
                    acc[co] = fmaf(p[k / 3][k % 3], wr[k], acc[co]);
            }
        }
        __syncthreads();
    }
#pragma unroll
    for (int co = 0; co < COB; ++co) {
        float v = acc[co] + bias[co0 + co];
        v = v > 0.f ? v : 0.f;
        out[(size_t)(co0 + co) * H * W + (size_t)oy * W + ox] = v;
    }
}

// ---------------------------------------------------------------------------
// conv2x2_k: 2x2 px/thread, 32x32 tile, 4 input channels per barrier stage,
// COB output channels per block. Weights staged in LDS. Used for H>=64.
// ---------------------------------------------------------------------------
template <int COB>
__global__ __launch_bounds__(256, 4) void conv2x2_k(
    const float* __restrict__ in, const float* __restrict__ wgt,
    const float* __restrict__ bias, float* __restrict__ out,
    int Cin, int Cout, int H, int W)
{
    const int tilesX = W >> 5;
    const int tx = blockIdx.x % tilesX;
    const int ty = blockIdx.x / tilesX;
    const int x0 = tx << 5, y0 = ty << 5;
    const int co0 = blockIdx.y * COB;
    const int n = blockIdx.z;
    in  += (size_t)n * Cin * H * W;
    out += (size_t)n * Cout * H * W;

    __shared__ float tile[4][34][36];
    __shared__ float wlds[4][COB][12];

    const int tid = threadIdx.x;
    const int lx = tid & 15, ly = tid >> 4;
    const int oy = y0 + 2 * ly, ox = x0 + 2 * lx;

    float acc[COB][2][2];
#pragma unroll
    for (int co = 0; co < COB; ++co)
#pragma unroll
        for (int dy = 0; dy < 2; ++dy)
#pragma unroll
            for (int dx = 0; dx < 2; ++dx) acc[co][dy][dx] = 0.f;

    for (int ci0 = 0; ci0 < Cin; ci0 += 4) {
        for (int t = tid; t < 4 * 1156; t += 256) {
            int s = t / 1156;
            int rem = t - s * 1156;
            int r = rem / 34, c = rem - r * 34;
            int gy = y0 - 1 + r, gx = x0 - 1 + c;
            const float* ip = in + (size_t)(ci0 + s) * H * W;
            float v = 0.f;
            if (gy >= 0 && gy < H && gx >= 0 && gx < W) v = ip[(size_t)gy * W + gx];
            tile[s][r][c] = v;
        }
        for (int t = tid; t < 4 * COB * 9; t += 256) {
            int co = t / 36;
            int r  = t - co * 36;
            int s  = r / 9, k = r - s * 9;
            wlds[s][co][k] = wgt[((size_t)(co0 + co) * Cin + (ci0 + s)) * 9 + k];
        }
        __syncthreads();
#pragma unroll
        for (int s = 0; s < 4; ++s) {
            float patch[4][4];
#pragma unroll
            for (int r = 0; r < 4; ++r) {
                const float* row = &tile[s][2 * ly + r][2 * lx];
#pragma unroll
                for (int c = 0; c < 4; ++c) patch[r][c] = row[c];
            }
#pragma unroll
            for (int co = 0; co < COB; ++co) {
                float wr[9];
#pragma unroll
                for (int k = 0; k < 9; ++k) wr[k] = wlds[s][co][k];
#pragma unroll
                for (int kr = 0; kr < 3; ++kr)
#pragma unroll
                    for (int kc = 0; kc < 3; ++kc) {
                        float wv = wr[kr * 3 + kc];
                        acc[co][0][0] = fmaf(patch[kr][kc],         wv, acc[co][0][0]);
                        acc[co][0][1] = fmaf(patch[kr][kc + 1],     wv, acc[co][0][1]);
                        acc[co][1][0] = fmaf(patch[kr + 1][kc],     wv, acc[co][1][0]);
                        acc[co][1][1] = fmaf(patch[kr + 1][kc + 1], wv, acc[co][1][1]);
                    }
            }
        }
        __syncthreads();
    }
#pragma unroll
    for (int co = 0; co < COB; ++co) {
        float bv = bias[co0 + co];
        float* op = out + (size_t)(co0 + co) * H * W + (size_t)oy * W + ox;
#pragma unroll
        for (int dy = 0; dy < 2; ++dy) {
            float v0 = acc[co][dy][0] + bv; v0 = v0 > 0.f ? v0 : 0.f;
            float v1 = acc[co][dy][1] + bv; v1 = v1 > 0.f ? v1 : 0.f;
            *reinterpret_cast<float2*>(op + (size_t)dy * W) = make_float2(v0, v1);
        }
    }
}

// 2x2 maxpool. W power of two; wshift = log2(W). grid: (pixels/256, Ct).
__global__ __launch_bounds__(256) void maxpool2x2_k(
    const float* __restrict__ in, float* __restrict__ out, int wshift)
{
    const int W = 1 << wshift, Wo = W >> 1;
    const int c = blockIdx.y;
    const int p = blockIdx.x * 256 + threadIdx.x;
    const int yo = p >> (wshift - 1);
    const int xo = p & (Wo - 1);
    const float* ip = in + ((size_t)c << (2 * wshift)) + (size_t)(2 * yo) * W + 2 * xo;
    float v0 = fmaxf(ip[0], ip[1]);
    float v1 = fmaxf(ip[W], ip[W + 1]);
    out[((size_t)c << (2 * wshift - 2)) + p] = fmaxf(v0, v1);
}

// Bilinear feature align replicating the reference's edge-weight quirks.
__global__ __launch_bounds__(256) void align_k(
    const float* __restrict__ feat, const float* __restrict__ pts,
    const int* __restrict__ mask, float* __restrict__ out,
    int B, int C, int H, int P)
{
    const int p = blockIdx.x, b = blockIdx.y;
    const int W = H;
    int ns = 0;
    for (int i = 0; i < P; ++i) ns += mask[b * P + i];
    const float valid = (p < ns) ? 1.f : 0.f;
    const float px = pts[((size_t)b * P + p) * 2 + 0];
    const float py = pts[((size_t)b * P + p) * 2 + 1];
    const float step = 256.0f / (float)H;
    const float x = (px - step * 0.5f) / 256.0f * (float)H;
    const float y = (py - step * 0.5f) / 256.0f * (float)W;
    const float x0f = floorf(x), y0f = floorf(y);
    const int x0 = min(max((int)x0f, 0), W - 1);
    const int x1 = min(max((int)x0f + 1, 0), W - 1);
    const int y0 = min(max((int)y0f, 0), H - 1);
    const int y1 = min(max((int)y0f + 1, 0), H - 1);
    const bool xe = (x0 == x1), ye = (y0 == y1);
    const float x0w = (xe && x0 == 0) ? -1.f : (float)x0;
    const float x1w = (xe && x0 != 0) ? (float)(x1 + 1) : (float)x1;
    const float y0w = (ye && y0 == 0) ? -1.f : (float)y0;
    const float y1w = (ye && y0 != 0) ? (float)(y1 + 1) : (float)y1;
    const float wa = (x1w - x) * (y1w - y);
    const float wb = (x1w - x) * (y - y0w);
    const float wc = (x - x0w) * (y1w - y);
    const float wd = (x - x0w) * (y - y0w);
    const float* f = feat + (size_t)b * C * H * W;
    for (int c = threadIdx.x; c < C; c += blockDim.x) {
        const float* fc = f + (size_t)c * H * W;
        float Ia = fc[y0 * W + x0];
        float Ib = fc[y1 * W + x0];
        float Ic = fc[y0 * W + x1];
        float Id = fc[y1 * W + x1];
        float v = Ia * wa + Ib * wb + Ic * wc + Id * wd;
        out[((size_t)b * P + p) * C + c] = v * valid;
    }
}

// Layer-shape-aware dispatch. Occupancy-first (r4 counters: occupancy 2.5-6%
// was the bottleneck): H>=64 -> 32x32-tile kernel; H<=32 -> 16x16 tile.
static inline void conv_auto(const float* in, const float* w, const float* b,
                             float* out, int N, int Cin, int Cout, int H,
                             hipStream_t s)
{
    if (Cin == 3) {
        int t = H >> 4;
        conv1_k<3, 8><<<dim3(t * t, Cout / 8, N), 256, 0, s>>>(in, w, b, out, Cin, Cout, H, H);
    } else if (H >= 64) {
        int t = H >> 5;
        conv2x2_k<8><<<dim3(t * t, Cout / 8, N), 256, 0, s>>>(in, w, b, out, Cin, Cout, H, H);
    } else {  // H == 32, 16
        int t = H >> 4;
        conv1_k<4, 8><<<dim3(t * t, Cout / 8, N), 256, 0, s>>>(in, w, b, out, Cin, Cout, H, H);
    }
}

static inline void launch_pool(const float* in, float* out, int Ct, int H,
                               hipStream_t s)
{
    int wshift = 31 - __builtin_clz((unsigned)H);
    int pixels = (H >> 1) * (H >> 1);
    dim3 g((pixels + 255) / 256, Ct);
    maxpool2x2_k<<<g, 256, 0, s>>>(in, out, wshift);
}

extern "C" void kernel_launch(void* const* d_in, const int* in_sizes, int n_in,
                              void* d_out, int out_size, void* d_ws, size_t ws_size,
                              hipStream_t stream)
{
    const float* x   = (const float*)d_in[0];
    const float* pts = (const float*)d_in[1];
    const int*   msk = (const int*)d_in[2];
    const float* w[11]; const float* bb[11];
    for (int i = 0; i < 11; ++i) {
        w[i]  = (const float*)d_in[3 + 2 * i];
        bb[i] = (const float*)d_in[4 + 2 * i];
    }
    float* out = (float*)d_out;
    float* ws = (float*)d_ws;

    // Tier A (84 MB): regions A(8.4M fl), B(4.2M fl), C(8.4M fl).
    //   stage1 per image: L0 x->C0, L1 C0->C1, pool -> A slice (pooled1)
    //   stage2 2-img groups: L2 A->C0, L3 C0->C1, pool -> B slice (pooled2)
    //   stage3 full batch: L4 B->A, L5 A->C, L6 C->A, pool A->C, L7 C->A,
    //                      L8 A->B (=F), L9 B->A, pool A->C, L10 C->A (=U)
    const size_t TA_FLOATS = 8388608ull + 4194304ull + 8388608ull;  // 21.0M fl

    const float* Fmap; const float* Umap;

    if (ws_size >= TA_FLOATS * 4) {
        float* A  = ws;                 // 8,388,608
        float* B  = A + 8388608;        // 4,194,304
        float* C  = B + 4194304;        // 8,388,608
        float* C0 = C;                  // 4,194,304
        float* C1 = C + 4194304;        // 4,194,304

        // stage 1: per image
        for (int n = 0; n < 8; ++n) {
            const float* xn = x + (size_t)n * 3 * 65536;
            conv_auto(xn, w[0], bb[0], C0, 1, 3, 64, 256, stream);
            conv_auto(C0, w[1], bb[1], C1, 1, 64, 64, 256, stream);
            launch_pool(C1, A + (size_t)n * 64 * 16384, 64, 256, stream);
        }
        // stage 2: 2-image groups
        for (int g = 0; g < 4; ++g) {
            const float* src = A + (size_t)g * 2 * 64 * 16384;
            conv_auto(src, w[2], bb[2], C0, 2, 64, 128, 128, stream);
            conv_auto(C0,  w[3], bb[3], C1, 2, 128, 128, 128, stream);
            launch_pool(C1, B + (size_t)g * 2 * 128 * 4096, 2 * 128, 128, stream);
        }
        // stage 3: full batch
        conv_auto(B, w[4], bb[4], A, 8, 128, 256, 64, stream);
        conv_auto(A, w[5], bb[5], C, 8, 256, 256, 64, stream);
        conv_auto(C, w[6], bb[6], A, 8, 256, 256, 64, stream);
        launch_pool(A, C, 8 * 256, 64, stream);               // 256@32^2
        conv_auto(C, w[7], bb[7], A, 8, 256, 512, 32, stream);
        conv_auto(A, w[8], bb[8], B, 8, 512, 512, 32, stream);  // F
        conv_auto(B, w[9], bb[9], A, 8, 512, 512, 32, stream);
        launch_pool(A, C, 8 * 512, 32, stream);               // 512@16^2
        conv_auto(C, w[10], bb[10], A, 8, 512, 512, 16, stream); // U
        Fmap = B; Umap = A;
    } else {
        // Per-image fallback (54.6 MB): p0, p1, F, U.
        float* p0 = ws;               // 4,194,304
        float* p1 = p0 + 4194304;     // 4,194,304
        float* F  = p1 + 4194304;     // 4,194,304
        float* U  = F + 4194304;      // 1,048,576
        for (int n = 0; n < 8; ++n) {
            const float* xn = x + (size_t)n * 3 * 65536;
            float* Fn = F + (size_t)n * 512 * 1024;
            float* Un = U + (size_t)n * 512 * 256;
            conv_auto(xn, w[0], bb[0], p0, 1, 3, 64, 256, stream);
            conv_auto(p0, w[1], bb[1], p1, 1, 64, 64, 256, stream);
            launch_pool(p1, p0, 64, 256, stream);
            conv_auto(p0, w[2], bb[2], p1, 1, 64, 128, 128, stream);
            conv_auto(p1, w[3], bb[3], p0, 1, 128, 128, 128, stream);
            launch_pool(p0, p1, 128, 128, stream);
            conv_auto(p1, w[4], bb[4], p0, 1, 128, 256, 64, stream);
            conv_auto(p0, w[5], bb[5], p1, 1, 256, 256, 64, stream);
            conv_auto(p1, w[6], bb[6], p0, 1, 256, 256, 64, stream);
            launch_pool(p0, p1, 256, 64, stream);
            conv_auto(p1, w[7], bb[7], p0, 1, 256, 512, 32, stream);
            conv_auto(p0, w[8], bb[8], Fn, 1, 512, 512, 32, stream);
            conv_auto(Fn, w[9], bb[9], p0, 1, 512, 512, 32, stream);
            launch_pool(p0, p1, 512, 32, stream);
            conv_auto(p1, w[10], bb[10], Un, 1, 512, 512, 16, stream);
        }
        Fmap = F; Umap = U;
    }

    dim3 g(32, 8);
    align_k<<<g, 256, 0, stream>>>(Fmap, pts, msk, out,          8, 512, 32, 32);
    align_k<<<g, 256, 0, stream>>>(Umap, pts, msk, out + 131072, 8, 512, 16, 32);
}